// Round 9
// baseline (154.048 us; speedup 1.0000x reference)
//
#include <hip/hip_runtime.h>

// DotProductAttention: B=16, NQ=2048, NK=2048, D=128, DV=128, fp32 in/out.
// R14: two-pass split-K to fix tail drain (occupancy stuck at exactly HALF
// structural ceiling in R7/R8/R13 = 512 blocks for 512 slots, wall = longest
// block 32 tiles vs balanced 16). Inner loop = R7 byte-identical. Tasks with
// ntiles>16 split into 2 half-range blocks (grid 1024 -> backfill; max block
// 16 tiles). NO inter-block sync (R9 lesson): pass1 writes UNNORMALIZED
// partials (h0 -> Out, h1 -> ws) + per-row l -> ws; pass2 streams add+
// normalize (~48MB, ~10us). convert_kv = R10 LDS-transpose (neutral, kept).

#define B_   16
#define NQ_  2048
#define NK_  2048
#define D_   128
#define DV_  128

typedef unsigned short ushort;
typedef __attribute__((ext_vector_type(4))) float          f32x4;
typedef __attribute__((ext_vector_type(8))) __bf16         bf16x8;
typedef __attribute__((ext_vector_type(8))) unsigned short ushort8v;
typedef __attribute__((ext_vector_type(4))) unsigned int   uint4v;

#ifdef __has_builtin
#if __has_builtin(__builtin_amdgcn_cvt_pk_bf16_f32)
#define HAVE_CVT_PK_BF16 1
#endif
#endif

__device__ __forceinline__ ushort f2bf(float f) {
    unsigned u = __builtin_bit_cast(unsigned, f);
    return (ushort)((u + 0x8000u) >> 16);
}
__device__ __forceinline__ unsigned f2bf2(float a, float b) {
#ifdef HAVE_CVT_PK_BF16
    auto t = __builtin_amdgcn_cvt_pk_bf16_f32(a, b);
    return __builtin_bit_cast(unsigned, t);
#else
    return (unsigned)f2bf(a) | ((unsigned)f2bf(b) << 16);
#endif
}
// sum of the two bf16 values packed in u (exactly the values PV consumes)
__device__ __forceinline__ float bfpair_sum(unsigned u) {
    float lo = __builtin_bit_cast(float, u << 16);
    float hi = __builtin_bit_cast(float, u & 0xffff0000u);
    return lo + hi;
}
__device__ __forceinline__ void gl_lds16(const ushort* g, ushort* l) {
    __builtin_amdgcn_global_load_lds(
        (const __attribute__((address_space(1))) void*)g,
        (__attribute__((address_space(3))) void*)l, 16, 0, 0);
}

// Pre-pass: per (b, k-tile): K -> bf16 tile [key64][d128], 16B-unit swizzle
// (d-unit du stored at du ^ (key&7)); V -> bf16 transposed [dv128][key64],
// key-unit kg stored at kg ^ (dv&7). V transposed via LDS.
#define VL_STRIDE 132
__global__ __launch_bounds__(256) void convert_kv(
    const float* __restrict__ K, const float* __restrict__ V,
    const int* __restrict__ vlen, ushort* __restrict__ Kb, ushort* __restrict__ Vtb)
{
    __shared__ ushort Vl[64 * VL_STRIDE];   // 16.5 KB
    const int id = blockIdx.x;              // 512 = 16 b x 32 tiles
    const int b  = id & 15, kt = id >> 4;
    if (kt >= ((vlen[b] + 63) >> 6)) return;
    const int tid = threadIdx.x;
    const float* gK = K + ((size_t)b * NK_ + kt * 64) * D_;
    const float* gV = V + ((size_t)b * NK_ + kt * 64) * DV_;
    ushort* tK = Kb  + ((size_t)b * 32 + kt) * 8192;
    ushort* tV = Vtb + ((size_t)b * 32 + kt) * 8192;

    #pragma unroll
    for (int i = 0; i < 4; ++i) {           // 1024 K units: key = u>>4, d-unit = u&15
        int u = i * 256 + tid;
        int key = u >> 4, d8 = u & 15;
        const float* p = gK + key * D_ + d8 * 8;
        f32x4 a0 = *(const f32x4*)p;
        f32x4 a1 = *(const f32x4*)(p + 4);
        uint4v w;
        w[0] = f2bf2(a0[0], a0[1]); w[1] = f2bf2(a0[2], a0[3]);
        w[2] = f2bf2(a1[0], a1[1]); w[3] = f2bf2(a1[2], a1[3]);
        *(uint4v*)&tK[key * 128 + ((d8 ^ (key & 7)) << 3)] = w;
    }

    // ---- V phase 1: coalesced row loads -> bf16 -> LDS [64][VL_STRIDE]
    #pragma unroll
    for (int i = 0; i < 4; ++i) {
        int u = i * 256 + tid;
        int key = u >> 4, d8 = u & 15;
        const float* p = gV + key * DV_ + d8 * 8;
        f32x4 a0 = *(const f32x4*)p;
        f32x4 a1 = *(const f32x4*)(p + 4);
        uint4v w;
        w[0] = f2bf2(a0[0], a0[1]); w[1] = f2bf2(a0[2], a0[3]);
        w[2] = f2bf2(a1[0], a1[1]); w[3] = f2bf2(a1[2], a1[3]);
        *(uint4v*)&Vl[key * VL_STRIDE + d8 * 8] = w;
    }
    __syncthreads();

    // ---- V phase 2: column gather from LDS, coalesced 16B writes to tV.
    #pragma unroll
    for (int i = 0; i < 4; ++i) {
        int u  = i * 256 + tid;             // 1024 units: c = u&7, dv = u>>3
        int c  = u & 7, dv = u >> 3;
        int kg = c ^ (dv & 7);
        ushort v[8];
        #pragma unroll
        for (int j = 0; j < 8; ++j) v[j] = Vl[(kg * 8 + j) * VL_STRIDE + dv];
        uint4v w;
        w[0] = (unsigned)v[0] | ((unsigned)v[1] << 16);
        w[1] = (unsigned)v[2] | ((unsigned)v[3] << 16);
        w[2] = (unsigned)v[4] | ((unsigned)v[5] << 16);
        w[3] = (unsigned)v[6] | ((unsigned)v[7] << 16);
        *(uint4v*)&tV[dv * 64 + c * 8] = w;
    }
}

// Pass 1: R7 inner loop, k-range [kt_lo, kt_hi). h0 -> Out (unnormalized),
// h1 -> wsO. Per-row l -> wsl[task][h][64]. No normalization here.
__global__ __launch_bounds__(512, 4) void attn_part(
    const float* __restrict__ Q, const int* __restrict__ vlen,
    const ushort* __restrict__ Kb, const ushort* __restrict__ Vtb,
    float* __restrict__ wsO, float* __restrict__ wsl,
    float* __restrict__ Out)
{
    // double-buffered K|V tiles (bf16, swizzled): [buf][ K 8192 | V 8192 ]
    __shared__ ushort KVbuf[2][16384];                 // 64 KB
    __shared__ float  lsh[2][64];
    __shared__ int    ssch[16];
    float* Osh = (float*)&KVbuf[0][0];                 // epilogue alias: [wk][64q][128dv]

    const int tid  = threadIdx.x;     // 0..511
    const int w    = tid >> 6;        // 0..7
    const int wq   = w >> 1;          // q-sixteenth owner (16 rows)
    const int wk   = w & 1;           // key-half (32 keys)
    const int L    = tid & 63;
    const int col  = L & 15;
    const int quad = L >> 4;

    // ---- inline schedule: rank batches by vl desc (deterministic)
    if (tid < 16) {
        int my = vlen[tid];
        int rank = 0;
        for (int o = 0; o < 16; ++o) {
            int vo = vlen[o];
            if (vo > my || (vo == my && o < tid)) ++rank;
        }
        ssch[rank] = tid;
    }
    __syncthreads();

    // ---- decode: grid 1024; halves adjacent so both halves of the biggest
    // tasks dispatch earliest; max block = 16 tiles -> backfill balances.
    const int e       = blockIdx.x;
    const int h       = e & 1;
    const int task    = e >> 1;            // 0..511
    const int r       = task & 15;         // rank (desc vl)
    const int qt      = task >> 4;         // 0..31
    const int b       = ssch[r];
    const int qbase   = qt * 64;
    const int vl      = vlen[b];
    const int ntiles  = (vl + 63) >> 6;
    const int split   = (ntiles > 16);
    if (!split && h) return;               // uniform exit: secondary unused
    const int hh    = (ntiles + 1) >> 1;
    const int kt_lo = (split && h) ? hh : 0;
    const int kt_hi = split ? (h ? ntiles : hh) : ntiles;

    // ---- Q fragments (16 rows/wave), pre-scaled by log2(e)/sqrt(128)
    const float qscale = 0.12751743f;
    bf16x8 qf[4];
    {
        const int qrow = qbase + wq * 16 + col;
        const float* gQ = Q + ((size_t)b * NQ_ + qrow) * D_;
        #pragma unroll
        for (int c = 0; c < 4; ++c) {
            const float* pp = gQ + c * 32 + quad * 8;
            f32x4 a0 = *(const f32x4*)pp;
            f32x4 a1 = *(const f32x4*)(pp + 4);
            uint4v us;
            us[0] = f2bf2(a0[0] * qscale, a0[1] * qscale);
            us[1] = f2bf2(a0[2] * qscale, a0[3] * qscale);
            us[2] = f2bf2(a1[0] * qscale, a1[1] * qscale);
            us[3] = f2bf2(a1[2] * qscale, a1[3] * qscale);
            qf[c] = __builtin_bit_cast(bf16x8, us);
        }
    }

    // ---- accumulators: partial O over own key-half, full 128 dv; scalar l
    f32x4 o[8];
    #pragma unroll
    for (int d = 0; d < 8; ++d) o[d] = (f32x4){0.f, 0.f, 0.f, 0.f};
    float l_run = 0.f;

    const ushort* tKb = Kb  + (size_t)b * 32 * 8192;
    const ushort* tVb = Vtb + (size_t)b * 32 * 8192;

    #define ISSUE_DMA(KT, BUF)                                               \
        do {                                                                 \
            const ushort* gk = tKb + (size_t)(KT) * 8192;                    \
            const ushort* gv = tVb + (size_t)(KT) * 8192;                    \
            _Pragma("unroll")                                                \
            for (int i = 0; i < 2; ++i) {                                    \
                int off = (i * 512 + tid) * 8;                               \
                gl_lds16(gk + off, &KVbuf[BUF][off]);                        \
                gl_lds16(gv + off, &KVbuf[BUF][8192 + off]);                 \
            }                                                                \
        } while (0)

    ISSUE_DMA(kt_lo, 0);

    const int swz = col & 7;

    for (int kt = kt_lo; kt < kt_hi; ++kt) {
        const int buf = (kt - kt_lo) & 1;
        __syncthreads();   // drains DMA(kt); prev readers done
        if (kt + 1 < kt_hi) ISSUE_DMA(kt + 1, buf ^ 1);

        const ushort* Kt = &KVbuf[buf][0];
        const ushort* Vt = &KVbuf[buf][8192];

        // ---- S^T = K Q^T (swapped): lane holds S[q=col][key=kc*16+quad*4+r]
        f32x4 s0 = (f32x4){0.f,0.f,0.f,0.f};
        f32x4 s1 = (f32x4){0.f,0.f,0.f,0.f};
        __builtin_amdgcn_s_setprio(1);
        {
            const int key0 = (wk * 32 + col) * 128;
            #pragma unroll
            for (int c = 0; c < 4; ++c) {
                bf16x8 kb = __builtin_bit_cast(bf16x8, *(const ushort8v*)
                    &Kt[key0 + (((c * 4 + quad) ^ swz) << 3)]);
                s0 = __builtin_amdgcn_mfma_f32_16x16x32_bf16(kb, qf[c], s0, 0, 0, 0);
            }
            #pragma unroll
            for (int c = 0; c < 4; ++c) {
                bf16x8 kb = __builtin_bit_cast(bf16x8, *(const ushort8v*)
                    &Kt[key0 + 16 * 128 + (((c * 4 + quad) ^ swz) << 3)]);
                s1 = __builtin_amdgcn_mfma_f32_16x16x32_bf16(kb, qf[c], s1, 0, 0, 0);
            }
        }
        __builtin_amdgcn_s_setprio(0);

        // ---- mask (key rows lane-indexed); exp2(-1e30) == 0
        const int rem = vl - kt * 64 - wk * 32;   // valid keys in this half
        if (rem < 32) {
            #pragma unroll
            for (int rr = 0; rr < 4; ++rr) {
                if (quad * 4 + rr >= rem)      s0[rr] = -1e30f;
                if (16 + quad * 4 + rr >= rem) s1[rr] = -1e30f;
            }
        }

        // ---- p = exp2(s) -> packed bf16; l sums the rounded values
        unsigned wA = f2bf2(exp2f(s0[0]), exp2f(s0[1]));
        unsigned wB = f2bf2(exp2f(s0[2]), exp2f(s0[3]));
        unsigned wC = f2bf2(exp2f(s1[0]), exp2f(s1[1]));
        unsigned wD = f2bf2(exp2f(s1[2]), exp2f(s1[3]));
        l_run += bfpair_sum(wA) + bfpair_sum(wB) + bfpair_sum(wC) + bfpair_sum(wD);

        // ---- in-register C-layout -> A-layout transpose across quads
        asm("v_permlane32_swap_b32 %0, %1" : "+v"(wA), "+v"(wC));
        asm("v_permlane32_swap_b32 %0, %1" : "+v"(wB), "+v"(wD));
        asm("v_permlane16_swap_b32 %0, %1" : "+v"(wA), "+v"(wC));
        asm("v_permlane16_swap_b32 %0, %1" : "+v"(wB), "+v"(wD));
        uint4v pw;
        pw[0] = wA; pw[1] = wB; pw[2] = wC; pw[3] = wD;
        bf16x8 pa = __builtin_bit_cast(bf16x8, pw);

        // ---- O_partial += P_own(16q x 32k) V_own(32k x 128dv)
        __builtin_amdgcn_s_setprio(1);
        #pragma unroll
        for (int dvc = 0; dvc < 8; ++dvc) {
            const int dv = dvc * 16 + col;
            bf16x8 vb = __builtin_bit_cast(bf16x8, *(const ushort8v*)
                &Vt[dv * 64 + (((wk * 4 + quad) ^ swz) << 3)]);
            o[dvc] = __builtin_amdgcn_mfma_f32_16x16x32_bf16(pa, vb, o[dvc], 0, 0, 0);
        }
        __builtin_amdgcn_s_setprio(0);
    }
    #undef ISSUE_DMA

    // ---- l: sum the 4 quads holding the same q=col
    l_run += __shfl_xor(l_run, 16, 64);
    l_run += __shfl_xor(l_run, 32, 64);

    __syncthreads();   // everyone done with KVbuf before aliasing as Osh

    if (L < 16) lsh[wk][wq * 16 + L] = l_run;
    #pragma unroll
    for (int dvc = 0; dvc < 8; ++dvc)
        #pragma unroll
        for (int rr = 0; rr < 4; ++rr)
            Osh[wk * 8192 + (wq * 16 + quad * 4 + rr) * 128 + dvc * 16 + col]
                = o[dvc][rr];
    __syncthreads();

    // ---- combine wk halves; write UNNORMALIZED sum (h0 -> Out, h1 -> wsO);
    // publish per-row l to wsl[task][h][64].
    if (tid < 64) wsl[(size_t)task * 128 + h * 64 + tid] = lsh[0][tid] + lsh[1][tid];
    float* dst = h ? (wsO + (size_t)task * 8192)
                   : (Out + ((size_t)b * NQ_ + qbase) * DV_);
    #pragma unroll
    for (int i = 0; i < 4; ++i) {
        int idx = i * 512 + tid;           // f32x4 chunk id, row-major
        int row = idx >> 5;
        int dq  = idx & 31;
        f32x4 a0 = *(const f32x4*)&Osh[row * 128 + dq * 4];
        f32x4 a1 = *(const f32x4*)&Osh[8192 + row * 128 + dq * 4];
        *(f32x4*)&dst[(size_t)row * 128 + dq * 4] = a0 + a1;
    }
}

// Pass 2: per task, Out = (Out + split? wsO) / (l0 + split? l1). Pure stream.
__global__ __launch_bounds__(256) void combine_norm(
    const int* __restrict__ vlen, const float* __restrict__ wsO,
    const float* __restrict__ wsl, float* __restrict__ Out)
{
    __shared__ int ssch[16];
    const int tid = threadIdx.x;
    if (tid < 16) {
        int my = vlen[tid];
        int rank = 0;
        for (int o = 0; o < 16; ++o) {
            int vo = vlen[o];
            if (vo > my || (vo == my && o < tid)) ++rank;
        }
        ssch[rank] = tid;
    }
    __syncthreads();

    const int task  = blockIdx.x;          // 0..511
    const int r     = task & 15;
    const int qt    = task >> 4;
    const int b     = ssch[r];
    const int vl    = vlen[b];
    const int split = (((vl + 63) >> 6) > 16);

    float* gO = Out + ((size_t)b * NQ_ + (size_t)qt * 64) * DV_;
    const float* pO = wsO + (size_t)task * 8192;
    const float* pl = wsl + (size_t)task * 128;

    #pragma unroll
    for (int i = 0; i < 8; ++i) {
        int idx = i * 256 + tid;           // f32x4 chunk id, 2048 total
        int row = idx >> 5;
        int dq  = idx & 31;
        f32x4 v = *(const f32x4*)&gO[(size_t)row * 128 + dq * 4];
        float l = pl[row];
        if (split) {
            v += *(const f32x4*)&pO[(size_t)row * 128 + dq * 4];
            l += pl[64 + row];
        }
        *(f32x4*)&gO[(size_t)row * 128 + dq * 4] = v * (1.0f / l);
    }
}

extern "C" void kernel_launch(void* const* d_in, const int* in_sizes, int n_in,
                              void* d_out, int out_size, void* d_ws, size_t ws_size,
                              hipStream_t stream) {
    const float* Q  = (const float*)d_in[0];
    const float* K  = (const float*)d_in[1];
    const float* V  = (const float*)d_in[2];
    const int*   vl = (const int*)d_in[3];
    float* out = (float*)d_out;

    // ws: [0, 256K) wsl (512x128 f32) | [256K, +16.78M) wsO (512x8192 f32) |
    //     [next, +8.39M) Kb | [next, +8.39M) Vtb   (~33.8 MB total)
    char* ws = (char*)d_ws;
    float*  wsl  = (float*)ws;
    float*  wsO  = (float*)(ws + 256 * 1024);
    ushort* Kbuf = (ushort*)(ws + 256 * 1024 + (size_t)512 * 8192 * 4);
    ushort* Vbuf = Kbuf + (size_t)B_ * 32 * 8192;

    convert_kv<<<dim3(512, 1, 1), dim3(256, 1, 1), 0, stream>>>(K, V, vl, Kbuf, Vbuf);
    attn_part<<<dim3(1024, 1, 1), dim3(512, 1, 1), 0, stream>>>(
        Q, vl, Kbuf, Vbuf, wsO, wsl, out);
    combine_norm<<<dim3(512, 1, 1), dim3(256, 1, 1), 0, stream>>>(
        vl, wsO, wsl, out);
}

// Round 10
// 130.309 us; speedup vs baseline: 1.1822x; 1.1822x over previous
//
#include <hip/hip_runtime.h>

// DotProductAttention: B=16, NQ=2048, NK=2048, D=128, DV=128, fp32 in/out.
// R15: R13 + two schedule-local tweaks (structure frozen after 6 structural
// regressions R8/R9/R11/R12/R14; R7/R13 inner loop best at 49.2us, x2 repro).
// (a) s_setprio REMOVED: m190 evidence says setprio hurts barrier-lockstep
//     structures (ours: 8 waves, 1 barrier/tile); it was added on the
//     independent-block attn precedent which doesn't apply here.
// (b) V fragments prefetched into regs right after QK MFMAs, BEFORE softmax:
//     8 ds_read_b128 have no dep on exp2/permlane chain -> LDS latency hides
//     under the serial softmax VALU (T14 mechanism). VGPR 52->~84 (free at
//     4 waves/SIMD). Everything else byte-identical to R13.

#define B_   16
#define NQ_  2048
#define NK_  2048
#define D_   128
#define DV_  128
#define NTASK_ 512

typedef unsigned short ushort;
typedef __attribute__((ext_vector_type(4))) float          f32x4;
typedef __attribute__((ext_vector_type(8))) __bf16         bf16x8;
typedef __attribute__((ext_vector_type(8))) unsigned short ushort8v;
typedef __attribute__((ext_vector_type(4))) unsigned int   uint4v;

#ifdef __has_builtin
#if __has_builtin(__builtin_amdgcn_cvt_pk_bf16_f32)
#define HAVE_CVT_PK_BF16 1
#endif
#endif

__device__ __forceinline__ ushort f2bf(float f) {
    unsigned u = __builtin_bit_cast(unsigned, f);
    return (ushort)((u + 0x8000u) >> 16);
}
__device__ __forceinline__ unsigned f2bf2(float a, float b) {
#ifdef HAVE_CVT_PK_BF16
    auto t = __builtin_amdgcn_cvt_pk_bf16_f32(a, b);
    return __builtin_bit_cast(unsigned, t);
#else
    return (unsigned)f2bf(a) | ((unsigned)f2bf(b) << 16);
#endif
}
// sum of the two bf16 values packed in u (exactly the values PV consumes)
__device__ __forceinline__ float bfpair_sum(unsigned u) {
    float lo = __builtin_bit_cast(float, u << 16);
    float hi = __builtin_bit_cast(float, u & 0xffff0000u);
    return lo + hi;
}
__device__ __forceinline__ void gl_lds16(const ushort* g, ushort* l) {
    __builtin_amdgcn_global_load_lds(
        (const __attribute__((address_space(1))) void*)g,
        (__attribute__((address_space(3))) void*)l, 16, 0, 0);
}

// Pre-pass: per (b, k-tile): K -> bf16 tile [key64][d128], 16B-unit swizzle
// (d-unit du stored at du ^ (key&7)); V -> bf16 transposed [dv128][key64],
// key-unit kg stored at kg ^ (dv&7). V transposed via LDS.
#define VL_STRIDE 132
__global__ __launch_bounds__(256) void convert_kv(
    const float* __restrict__ K, const float* __restrict__ V,
    const int* __restrict__ vlen, ushort* __restrict__ Kb, ushort* __restrict__ Vtb)
{
    __shared__ ushort Vl[64 * VL_STRIDE];   // 16.5 KB
    const int id = blockIdx.x;              // 512 = 16 b x 32 tiles
    const int b  = id & 15, kt = id >> 4;
    if (kt >= ((vlen[b] + 63) >> 6)) return;
    const int tid = threadIdx.x;
    const float* gK = K + ((size_t)b * NK_ + kt * 64) * D_;
    const float* gV = V + ((size_t)b * NK_ + kt * 64) * DV_;
    ushort* tK = Kb  + ((size_t)b * 32 + kt) * 8192;
    ushort* tV = Vtb + ((size_t)b * 32 + kt) * 8192;

    #pragma unroll
    for (int i = 0; i < 4; ++i) {           // 1024 K units: key = u>>4, d-unit = u&15
        int u = i * 256 + tid;
        int key = u >> 4, d8 = u & 15;
        const float* p = gK + key * D_ + d8 * 8;
        f32x4 a0 = *(const f32x4*)p;
        f32x4 a1 = *(const f32x4*)(p + 4);
        uint4v w;
        w[0] = f2bf2(a0[0], a0[1]); w[1] = f2bf2(a0[2], a0[3]);
        w[2] = f2bf2(a1[0], a1[1]); w[3] = f2bf2(a1[2], a1[3]);
        *(uint4v*)&tK[key * 128 + ((d8 ^ (key & 7)) << 3)] = w;
    }

    // ---- V phase 1: coalesced row loads -> bf16 -> LDS [64][VL_STRIDE]
    #pragma unroll
    for (int i = 0; i < 4; ++i) {
        int u = i * 256 + tid;
        int key = u >> 4, d8 = u & 15;
        const float* p = gV + key * DV_ + d8 * 8;
        f32x4 a0 = *(const f32x4*)p;
        f32x4 a1 = *(const f32x4*)(p + 4);
        uint4v w;
        w[0] = f2bf2(a0[0], a0[1]); w[1] = f2bf2(a0[2], a0[3]);
        w[2] = f2bf2(a1[0], a1[1]); w[3] = f2bf2(a1[2], a1[3]);
        *(uint4v*)&Vl[key * VL_STRIDE + d8 * 8] = w;
    }
    __syncthreads();

    // ---- V phase 2: column gather from LDS, coalesced 16B writes to tV.
    #pragma unroll
    for (int i = 0; i < 4; ++i) {
        int u  = i * 256 + tid;             // 1024 units: c = u&7, dv = u>>3
        int c  = u & 7, dv = u >> 3;
        int kg = c ^ (dv & 7);
        ushort v[8];
        #pragma unroll
        for (int j = 0; j < 8; ++j) v[j] = Vl[(kg * 8 + j) * VL_STRIDE + dv];
        uint4v w;
        w[0] = (unsigned)v[0] | ((unsigned)v[1] << 16);
        w[1] = (unsigned)v[2] | ((unsigned)v[3] << 16);
        w[2] = (unsigned)v[4] | ((unsigned)v[5] << 16);
        w[3] = (unsigned)v[6] | ((unsigned)v[7] << 16);
        *(uint4v*)&tV[dv * 64 + c * 8] = w;
    }
}

__global__ __launch_bounds__(512, 4) void attn_fwd(
    const float* __restrict__ Q, const int* __restrict__ vlen,
    const ushort* __restrict__ Kb, const ushort* __restrict__ Vtb,
    float* __restrict__ Out)
{
    // double-buffered K|V tiles (bf16, swizzled): [buf][ K 8192 | V 8192 ]
    __shared__ ushort KVbuf[2][16384];                 // 64 KB
    __shared__ float  lsh[2][64];
    __shared__ int    ssch[16];
    float* Osh = (float*)&KVbuf[0][0];                 // epilogue alias: [wk][64q][128dv]

    const int tid  = threadIdx.x;     // 0..511
    const int w    = tid >> 6;        // 0..7
    const int wq   = w >> 1;          // q-sixteenth owner (16 rows)
    const int wk   = w & 1;           // key-half (32 keys)
    const int L    = tid & 63;
    const int col  = L & 15;
    const int quad = L >> 4;

    // ---- inline schedule: rank batches by vl desc
    if (tid < 16) {
        int my = vlen[tid];
        int rank = 0;
        for (int o = 0; o < 16; ++o) {
            int vo = vlen[o];
            if (vo > my || (vo == my && o < tid)) ++rank;
        }
        ssch[rank] = tid;
    }
    __syncthreads();

    // ---- R7 decode: pair rank p with 15-p; halves e and e+256.
    const int e     = blockIdx.x;
    const int p_    = (e & 255) >> 5;
    const int b     = (e >> 8) ? ssch[15 - p_] : ssch[p_];
    const int qbase = (e & 31) * 64;
    const int vl    = vlen[b];
    const int ntiles = (vl + 63) >> 6;

    // ---- Q fragments (16 rows/wave), pre-scaled by log2(e)/sqrt(128)
    const float qscale = 0.12751743f;
    bf16x8 qf[4];
    {
        const int qrow = qbase + wq * 16 + col;
        const float* gQ = Q + ((size_t)b * NQ_ + qrow) * D_;
        #pragma unroll
        for (int c = 0; c < 4; ++c) {
            const float* pp = gQ + c * 32 + quad * 8;
            f32x4 a0 = *(const f32x4*)pp;
            f32x4 a1 = *(const f32x4*)(pp + 4);
            uint4v us;
            us[0] = f2bf2(a0[0] * qscale, a0[1] * qscale);
            us[1] = f2bf2(a0[2] * qscale, a0[3] * qscale);
            us[2] = f2bf2(a1[0] * qscale, a1[1] * qscale);
            us[3] = f2bf2(a1[2] * qscale, a1[3] * qscale);
            qf[c] = __builtin_bit_cast(bf16x8, us);
        }
    }

    // ---- accumulators: partial O over own key-half, full 128 dv; scalar l
    f32x4 o[8];
    #pragma unroll
    for (int d = 0; d < 8; ++d) o[d] = (f32x4){0.f, 0.f, 0.f, 0.f};
    float l_run = 0.f;

    const ushort* tKb = Kb  + (size_t)b * 32 * 8192;
    const ushort* tVb = Vtb + (size_t)b * 32 * 8192;

    #define ISSUE_DMA(KT, BUF)                                               \
        do {                                                                 \
            const ushort* gk = tKb + (size_t)(KT) * 8192;                    \
            const ushort* gv = tVb + (size_t)(KT) * 8192;                    \
            _Pragma("unroll")                                                \
            for (int i = 0; i < 2; ++i) {                                    \
                int off = (i * 512 + tid) * 8;                               \
                gl_lds16(gk + off, &KVbuf[BUF][off]);                        \
                gl_lds16(gv + off, &KVbuf[BUF][8192 + off]);                 \
            }                                                                \
        } while (0)

    ISSUE_DMA(0, 0);

    const int swz = col & 7;

    for (int kt = 0; kt < ntiles; ++kt) {
        const int buf = kt & 1;
        __syncthreads();   // drains DMA(kt); prev readers done
        if (kt + 1 < ntiles) ISSUE_DMA(kt + 1, buf ^ 1);

        const ushort* Kt = &KVbuf[buf][0];
        const ushort* Vt = &KVbuf[buf][8192];

        // ---- S^T = K Q^T (swapped): lane holds S[q=col][key=kc*16+quad*4+r]
        f32x4 s0 = (f32x4){0.f,0.f,0.f,0.f};
        f32x4 s1 = (f32x4){0.f,0.f,0.f,0.f};
        {
            const int key0 = (wk * 32 + col) * 128;
            #pragma unroll
            for (int c = 0; c < 4; ++c) {
                bf16x8 kb = __builtin_bit_cast(bf16x8, *(const ushort8v*)
                    &Kt[key0 + (((c * 4 + quad) ^ swz) << 3)]);
                s0 = __builtin_amdgcn_mfma_f32_16x16x32_bf16(kb, qf[c], s0, 0, 0, 0);
            }
            #pragma unroll
            for (int c = 0; c < 4; ++c) {
                bf16x8 kb = __builtin_bit_cast(bf16x8, *(const ushort8v*)
                    &Kt[key0 + 16 * 128 + (((c * 4 + quad) ^ swz) << 3)]);
                s1 = __builtin_amdgcn_mfma_f32_16x16x32_bf16(kb, qf[c], s1, 0, 0, 0);
            }
        }

        // ---- prefetch V fragments NOW (no dep on softmax): LDS latency
        // hides under the exp2/permlane serial chain below.
        bf16x8 vbr[8];
        #pragma unroll
        for (int dvc = 0; dvc < 8; ++dvc) {
            const int dv = dvc * 16 + col;
            vbr[dvc] = __builtin_bit_cast(bf16x8, *(const ushort8v*)
                &Vt[dv * 64 + (((wk * 4 + quad) ^ swz) << 3)]);
        }

        // ---- mask (key rows lane-indexed); exp2(-1e30) == 0
        const int rem = vl - kt * 64 - wk * 32;   // valid keys in this half
        if (rem < 32) {
            #pragma unroll
            for (int rr = 0; rr < 4; ++rr) {
                if (quad * 4 + rr >= rem)      s0[rr] = -1e30f;
                if (16 + quad * 4 + rr >= rem) s1[rr] = -1e30f;
            }
        }

        // ---- p = exp2(s) -> packed bf16; l sums the rounded values
        unsigned wA = f2bf2(exp2f(s0[0]), exp2f(s0[1]));
        unsigned wB = f2bf2(exp2f(s0[2]), exp2f(s0[3]));
        unsigned wC = f2bf2(exp2f(s1[0]), exp2f(s1[1]));
        unsigned wD = f2bf2(exp2f(s1[2]), exp2f(s1[3]));
        l_run += bfpair_sum(wA) + bfpair_sum(wB) + bfpair_sum(wC) + bfpair_sum(wD);

        // ---- in-register C-layout -> A-layout transpose across quads
        asm("v_permlane32_swap_b32 %0, %1" : "+v"(wA), "+v"(wC));
        asm("v_permlane32_swap_b32 %0, %1" : "+v"(wB), "+v"(wD));
        asm("v_permlane16_swap_b32 %0, %1" : "+v"(wA), "+v"(wC));
        asm("v_permlane16_swap_b32 %0, %1" : "+v"(wB), "+v"(wD));
        uint4v pw;
        pw[0] = wA; pw[1] = wB; pw[2] = wC; pw[3] = wD;
        bf16x8 pa = __builtin_bit_cast(bf16x8, pw);

        // ---- O_partial += P_own(16q x 32k) V_own(32k x 128dv)
        #pragma unroll
        for (int dvc = 0; dvc < 8; ++dvc)
            o[dvc] = __builtin_amdgcn_mfma_f32_16x16x32_bf16(pa, vbr[dvc], o[dvc], 0, 0, 0);
    }
    #undef ISSUE_DMA

    // ---- l: sum the 4 quads holding the same q=col
    l_run += __shfl_xor(l_run, 16, 64);
    l_run += __shfl_xor(l_run, 32, 64);

    __syncthreads();   // everyone done with KVbuf before aliasing as Osh

    if (L < 16) lsh[wk][wq * 16 + L] = l_run;
    #pragma unroll
    for (int dvc = 0; dvc < 8; ++dvc)
        #pragma unroll
        for (int rr = 0; rr < 4; ++rr)
            Osh[wk * 8192 + (wq * 16 + quad * 4 + rr) * 128 + dvc * 16 + col]
                = o[dvc][rr];
    __syncthreads();

    // ---- combine wk halves, normalize, coalesced store
    float* gO = Out + ((size_t)b * NQ_ + qbase) * DV_;
    #pragma unroll
    for (int i = 0; i < 4; ++i) {
        int idx = i * 512 + tid;           // f32x4 chunk id, row-major
        int row = idx >> 5;
        int dq  = idx & 31;
        f32x4 a0 = *(const f32x4*)&Osh[row * 128 + dq * 4];
        f32x4 a1 = *(const f32x4*)&Osh[8192 + row * 128 + dq * 4];
        float linv = 1.0f / (lsh[0][row] + lsh[1][row]);
        *(f32x4*)&gO[(size_t)row * DV_ + dq * 4] = (a0 + a1) * linv;
    }
}

extern "C" void kernel_launch(void* const* d_in, const int* in_sizes, int n_in,
                              void* d_out, int out_size, void* d_ws, size_t ws_size,
                              hipStream_t stream) {
    const float* Q  = (const float*)d_in[0];
    const float* K  = (const float*)d_in[1];
    const float* V  = (const float*)d_in[2];
    const int*   vl = (const int*)d_in[3];
    float* out = (float*)d_out;

    // ws: [0,4K) reserved | [4K, +8.39M) Kb | [next, +8.39M) Vtb  (~16.8 MB)
    char* ws = (char*)d_ws;
    ushort* Kbuf = (ushort*)(ws + 4096);
    ushort* Vbuf = Kbuf + (size_t)B_ * 32 * 8192;

    convert_kv<<<dim3(512, 1, 1), dim3(256, 1, 1), 0, stream>>>(K, V, vl, Kbuf, Vbuf);
    attn_fwd<<<dim3(NTASK_, 1, 1), dim3(512, 1, 1), 0, stream>>>(
        Q, vl, Kbuf, Vbuf, out);
}

// Round 11
// 127.748 us; speedup vs baseline: 1.2059x; 1.0200x over previous
//
#include <hip/hip_runtime.h>

// DotProductAttention: B=16, NQ=2048, NK=2048, D=128, DV=128, fp32 in/out.
// R16: R15 + three latency-hiding / strength-reduction micro-tweaks (attn
// structure frozen; R15 = best, 46.9us attn / 130.3 total).
// (a) ALL 8 K-fragment ds_reads hoisted above both QK MFMA chains (R15's
//     V-prefetch mechanism applied to K);
// (b) exp2 via raw v_exp_f32 asm (avoids possible OCML wrapper; args bounded,
//     -1e30 -> 0 preserved);
// (c) ISSUE_DMA(0) moved before Q-fragment load so first-tile HBM latency
//     hides under Q prep. Everything else byte-identical to R15.

#define B_   16
#define NQ_  2048
#define NK_  2048
#define D_   128
#define DV_  128
#define NTASK_ 512

typedef unsigned short ushort;
typedef __attribute__((ext_vector_type(4))) float          f32x4;
typedef __attribute__((ext_vector_type(8))) __bf16         bf16x8;
typedef __attribute__((ext_vector_type(8))) unsigned short ushort8v;
typedef __attribute__((ext_vector_type(4))) unsigned int   uint4v;

#ifdef __has_builtin
#if __has_builtin(__builtin_amdgcn_cvt_pk_bf16_f32)
#define HAVE_CVT_PK_BF16 1
#endif
#endif

__device__ __forceinline__ ushort f2bf(float f) {
    unsigned u = __builtin_bit_cast(unsigned, f);
    return (ushort)((u + 0x8000u) >> 16);
}
__device__ __forceinline__ unsigned f2bf2(float a, float b) {
#ifdef HAVE_CVT_PK_BF16
    auto t = __builtin_amdgcn_cvt_pk_bf16_f32(a, b);
    return __builtin_bit_cast(unsigned, t);
#else
    return (unsigned)f2bf(a) | ((unsigned)f2bf(b) << 16);
#endif
}
// sum of the two bf16 values packed in u (exactly the values PV consumes)
__device__ __forceinline__ float bfpair_sum(unsigned u) {
    float lo = __builtin_bit_cast(float, u << 16);
    float hi = __builtin_bit_cast(float, u & 0xffff0000u);
    return lo + hi;
}
// raw HW exp2: v_exp_f32 computes 2^x exactly; handles -1e30 -> 0, no wrapper.
__device__ __forceinline__ float exp2_hw(float x) {
    float r;
    asm("v_exp_f32 %0, %1" : "=v"(r) : "v"(x));
    return r;
}
__device__ __forceinline__ void gl_lds16(const ushort* g, ushort* l) {
    __builtin_amdgcn_global_load_lds(
        (const __attribute__((address_space(1))) void*)g,
        (__attribute__((address_space(3))) void*)l, 16, 0, 0);
}

// Pre-pass: per (b, k-tile): K -> bf16 tile [key64][d128], 16B-unit swizzle
// (d-unit du stored at du ^ (key&7)); V -> bf16 transposed [dv128][key64],
// key-unit kg stored at kg ^ (dv&7). V transposed via LDS.
#define VL_STRIDE 132
__global__ __launch_bounds__(256) void convert_kv(
    const float* __restrict__ K, const float* __restrict__ V,
    const int* __restrict__ vlen, ushort* __restrict__ Kb, ushort* __restrict__ Vtb)
{
    __shared__ ushort Vl[64 * VL_STRIDE];   // 16.5 KB
    const int id = blockIdx.x;              // 512 = 16 b x 32 tiles
    const int b  = id & 15, kt = id >> 4;
    if (kt >= ((vlen[b] + 63) >> 6)) return;
    const int tid = threadIdx.x;
    const float* gK = K + ((size_t)b * NK_ + kt * 64) * D_;
    const float* gV = V + ((size_t)b * NK_ + kt * 64) * DV_;
    ushort* tK = Kb  + ((size_t)b * 32 + kt) * 8192;
    ushort* tV = Vtb + ((size_t)b * 32 + kt) * 8192;

    #pragma unroll
    for (int i = 0; i < 4; ++i) {           // 1024 K units: key = u>>4, d-unit = u&15
        int u = i * 256 + tid;
        int key = u >> 4, d8 = u & 15;
        const float* p = gK + key * D_ + d8 * 8;
        f32x4 a0 = *(const f32x4*)p;
        f32x4 a1 = *(const f32x4*)(p + 4);
        uint4v w;
        w[0] = f2bf2(a0[0], a0[1]); w[1] = f2bf2(a0[2], a0[3]);
        w[2] = f2bf2(a1[0], a1[1]); w[3] = f2bf2(a1[2], a1[3]);
        *(uint4v*)&tK[key * 128 + ((d8 ^ (key & 7)) << 3)] = w;
    }

    // ---- V phase 1: coalesced row loads -> bf16 -> LDS [64][VL_STRIDE]
    #pragma unroll
    for (int i = 0; i < 4; ++i) {
        int u = i * 256 + tid;
        int key = u >> 4, d8 = u & 15;
        const float* p = gV + key * DV_ + d8 * 8;
        f32x4 a0 = *(const f32x4*)p;
        f32x4 a1 = *(const f32x4*)(p + 4);
        uint4v w;
        w[0] = f2bf2(a0[0], a0[1]); w[1] = f2bf2(a0[2], a0[3]);
        w[2] = f2bf2(a1[0], a1[1]); w[3] = f2bf2(a1[2], a1[3]);
        *(uint4v*)&Vl[key * VL_STRIDE + d8 * 8] = w;
    }
    __syncthreads();

    // ---- V phase 2: column gather from LDS, coalesced 16B writes to tV.
    #pragma unroll
    for (int i = 0; i < 4; ++i) {
        int u  = i * 256 + tid;             // 1024 units: c = u&7, dv = u>>3
        int c  = u & 7, dv = u >> 3;
        int kg = c ^ (dv & 7);
        ushort v[8];
        #pragma unroll
        for (int j = 0; j < 8; ++j) v[j] = Vl[(kg * 8 + j) * VL_STRIDE + dv];
        uint4v w;
        w[0] = (unsigned)v[0] | ((unsigned)v[1] << 16);
        w[1] = (unsigned)v[2] | ((unsigned)v[3] << 16);
        w[2] = (unsigned)v[4] | ((unsigned)v[5] << 16);
        w[3] = (unsigned)v[6] | ((unsigned)v[7] << 16);
        *(uint4v*)&tV[dv * 64 + c * 8] = w;
    }
}

__global__ __launch_bounds__(512, 4) void attn_fwd(
    const float* __restrict__ Q, const int* __restrict__ vlen,
    const ushort* __restrict__ Kb, const ushort* __restrict__ Vtb,
    float* __restrict__ Out)
{
    // double-buffered K|V tiles (bf16, swizzled): [buf][ K 8192 | V 8192 ]
    __shared__ ushort KVbuf[2][16384];                 // 64 KB
    __shared__ float  lsh[2][64];
    __shared__ int    ssch[16];
    float* Osh = (float*)&KVbuf[0][0];                 // epilogue alias: [wk][64q][128dv]

    const int tid  = threadIdx.x;     // 0..511
    const int w    = tid >> 6;        // 0..7
    const int wq   = w >> 1;          // q-sixteenth owner (16 rows)
    const int wk   = w & 1;           // key-half (32 keys)
    const int L    = tid & 63;
    const int col  = L & 15;
    const int quad = L >> 4;

    // ---- inline schedule: rank batches by vl desc
    if (tid < 16) {
        int my = vlen[tid];
        int rank = 0;
        for (int o = 0; o < 16; ++o) {
            int vo = vlen[o];
            if (vo > my || (vo == my && o < tid)) ++rank;
        }
        ssch[rank] = tid;
    }
    __syncthreads();

    // ---- R7 decode: pair rank p with 15-p; halves e and e+256.
    const int e     = blockIdx.x;
    const int p_    = (e & 255) >> 5;
    const int b     = (e >> 8) ? ssch[15 - p_] : ssch[p_];
    const int qbase = (e & 31) * 64;
    const int vl    = vlen[b];
    const int ntiles = (vl + 63) >> 6;

    const ushort* tKb = Kb  + (size_t)b * 32 * 8192;
    const ushort* tVb = Vtb + (size_t)b * 32 * 8192;

    #define ISSUE_DMA(KT, BUF)                                               \
        do {                                                                 \
            const ushort* gk = tKb + (size_t)(KT) * 8192;                    \
            const ushort* gv = tVb + (size_t)(KT) * 8192;                    \
            _Pragma("unroll")                                                \
            for (int i = 0; i < 2; ++i) {                                    \
                int off = (i * 512 + tid) * 8;                               \
                gl_lds16(gk + off, &KVbuf[BUF][off]);                        \
                gl_lds16(gv + off, &KVbuf[BUF][8192 + off]);                 \
            }                                                                \
        } while (0)

    // first-tile DMA issued BEFORE Q prep: HBM latency hides under Q load/convert
    ISSUE_DMA(0, 0);

    // ---- Q fragments (16 rows/wave), pre-scaled by log2(e)/sqrt(128)
    const float qscale = 0.12751743f;
    bf16x8 qf[4];
    {
        const int qrow = qbase + wq * 16 + col;
        const float* gQ = Q + ((size_t)b * NQ_ + qrow) * D_;
        #pragma unroll
        for (int c = 0; c < 4; ++c) {
            const float* pp = gQ + c * 32 + quad * 8;
            f32x4 a0 = *(const f32x4*)pp;
            f32x4 a1 = *(const f32x4*)(pp + 4);
            uint4v us;
            us[0] = f2bf2(a0[0] * qscale, a0[1] * qscale);
            us[1] = f2bf2(a0[2] * qscale, a0[3] * qscale);
            us[2] = f2bf2(a1[0] * qscale, a1[1] * qscale);
            us[3] = f2bf2(a1[2] * qscale, a1[3] * qscale);
            qf[c] = __builtin_bit_cast(bf16x8, us);
        }
    }

    // ---- accumulators: partial O over own key-half, full 128 dv; scalar l
    f32x4 o[8];
    #pragma unroll
    for (int d = 0; d < 8; ++d) o[d] = (f32x4){0.f, 0.f, 0.f, 0.f};
    float l_run = 0.f;

    const int swz = col & 7;

    for (int kt = 0; kt < ntiles; ++kt) {
        const int buf = kt & 1;
        __syncthreads();   // drains DMA(kt); prev readers done
        if (kt + 1 < ntiles) ISSUE_DMA(kt + 1, buf ^ 1);

        const ushort* Kt = &KVbuf[buf][0];
        const ushort* Vt = &KVbuf[buf][8192];

        // ---- ALL 8 K-fragment reads first (in flight before MFMAs need them)
        const int key0 = (wk * 32 + col) * 128;
        bf16x8 kb0[4], kb1[4];
        #pragma unroll
        for (int c = 0; c < 4; ++c) {
            kb0[c] = __builtin_bit_cast(bf16x8, *(const ushort8v*)
                &Kt[key0 + (((c * 4 + quad) ^ swz) << 3)]);
            kb1[c] = __builtin_bit_cast(bf16x8, *(const ushort8v*)
                &Kt[key0 + 16 * 128 + (((c * 4 + quad) ^ swz) << 3)]);
        }

        // ---- S^T = K Q^T (swapped): lane holds S[q=col][key=kc*16+quad*4+r]
        f32x4 s0 = (f32x4){0.f,0.f,0.f,0.f};
        f32x4 s1 = (f32x4){0.f,0.f,0.f,0.f};
        #pragma unroll
        for (int c = 0; c < 4; ++c) {
            s0 = __builtin_amdgcn_mfma_f32_16x16x32_bf16(kb0[c], qf[c], s0, 0, 0, 0);
            s1 = __builtin_amdgcn_mfma_f32_16x16x32_bf16(kb1[c], qf[c], s1, 0, 0, 0);
        }

        // ---- prefetch V fragments NOW (no dep on softmax): LDS latency
        // hides under the exp2/permlane serial chain below.
        bf16x8 vbr[8];
        #pragma unroll
        for (int dvc = 0; dvc < 8; ++dvc) {
            const int dv = dvc * 16 + col;
            vbr[dvc] = __builtin_bit_cast(bf16x8, *(const ushort8v*)
                &Vt[dv * 64 + (((wk * 4 + quad) ^ swz) << 3)]);
        }

        // ---- mask (key rows lane-indexed); exp2(-1e30) == 0
        const int rem = vl - kt * 64 - wk * 32;   // valid keys in this half
        if (rem < 32) {
            #pragma unroll
            for (int rr = 0; rr < 4; ++rr) {
                if (quad * 4 + rr >= rem)      s0[rr] = -1e30f;
                if (16 + quad * 4 + rr >= rem) s1[rr] = -1e30f;
            }
        }

        // ---- p = exp2(s) -> packed bf16; l sums the rounded values
        unsigned wA = f2bf2(exp2_hw(s0[0]), exp2_hw(s0[1]));
        unsigned wB = f2bf2(exp2_hw(s0[2]), exp2_hw(s0[3]));
        unsigned wC = f2bf2(exp2_hw(s1[0]), exp2_hw(s1[1]));
        unsigned wD = f2bf2(exp2_hw(s1[2]), exp2_hw(s1[3]));
        l_run += bfpair_sum(wA) + bfpair_sum(wB) + bfpair_sum(wC) + bfpair_sum(wD);

        // ---- in-register C-layout -> A-layout transpose across quads
        asm("v_permlane32_swap_b32 %0, %1" : "+v"(wA), "+v"(wC));
        asm("v_permlane32_swap_b32 %0, %1" : "+v"(wB), "+v"(wD));
        asm("v_permlane16_swap_b32 %0, %1" : "+v"(wA), "+v"(wC));
        asm("v_permlane16_swap_b32 %0, %1" : "+v"(wB), "+v"(wD));
        uint4v pw;
        pw[0] = wA; pw[1] = wB; pw[2] = wC; pw[3] = wD;
        bf16x8 pa = __builtin_bit_cast(bf16x8, pw);

        // ---- O_partial += P_own(16q x 32k) V_own(32k x 128dv)
        #pragma unroll
        for (int dvc = 0; dvc < 8; ++dvc)
            o[dvc] = __builtin_amdgcn_mfma_f32_16x16x32_bf16(pa, vbr[dvc], o[dvc], 0, 0, 0);
    }
    #undef ISSUE_DMA

    // ---- l: sum the 4 quads holding the same q=col
    l_run += __shfl_xor(l_run, 16, 64);
    l_run += __shfl_xor(l_run, 32, 64);

    __syncthreads();   // everyone done with KVbuf before aliasing as Osh

    if (L < 16) lsh[wk][wq * 16 + L] = l_run;
    #pragma unroll
    for (int dvc = 0; dvc < 8; ++dvc)
        #pragma unroll
        for (int rr = 0; rr < 4; ++rr)
            Osh[wk * 8192 + (wq * 16 + quad * 4 + rr) * 128 + dvc * 16 + col]
                = o[dvc][rr];
    __syncthreads();

    // ---- combine wk halves, normalize, coalesced store
    float* gO = Out + ((size_t)b * NQ_ + qbase) * DV_;
    #pragma unroll
    for (int i = 0; i < 4; ++i) {
        int idx = i * 512 + tid;           // f32x4 chunk id, row-major
        int row = idx >> 5;
        int dq  = idx & 31;
        f32x4 a0 = *(const f32x4*)&Osh[row * 128 + dq * 4];
        f32x4 a1 = *(const f32x4*)&Osh[8192 + row * 128 + dq * 4];
        float linv = 1.0f / (lsh[0][row] + lsh[1][row]);
        *(f32x4*)&gO[(size_t)row * DV_ + dq * 4] = (a0 + a1) * linv;
    }
}

extern "C" void kernel_launch(void* const* d_in, const int* in_sizes, int n_in,
                              void* d_out, int out_size, void* d_ws, size_t ws_size,
                              hipStream_t stream) {
    const float* Q  = (const float*)d_in[0];
    const float* K  = (const float*)d_in[1];
    const float* V  = (const float*)d_in[2];
    const int*   vl = (const int*)d_in[3];
    float* out = (float*)d_out;

    // ws: [0,4K) reserved | [4K, +8.39M) Kb | [next, +8.39M) Vtb  (~16.8 MB)
    char* ws = (char*)d_ws;
    ushort* Kbuf = (ushort*)(ws + 4096);
    ushort* Vbuf = Kbuf + (size_t)B_ * 32 * 8192;

    convert_kv<<<dim3(512, 1, 1), dim3(256, 1, 1), 0, stream>>>(K, V, vl, Kbuf, Vbuf);
    attn_fwd<<<dim3(NTASK_, 1, 1), dim3(512, 1, 1), 0, stream>>>(
        Q, vl, Kbuf, Vbuf, out);
}

// Round 13
// 126.871 us; speedup vs baseline: 1.2142x; 1.0069x over previous
//
#include <hip/hip_runtime.h>

// DotProductAttention: B=16, NQ=2048, NK=2048, D=128, DV=128, fp32 in/out.
// R18: R17 (rowsum-via-MFMA) with the permlane transpose moved from inline
// asm to __builtin_amdgcn_permlane{32,16}_swap. R17's absmax-1.05 failure is
// attributed to the VALU(inline-asm)->MFMA read hazard: asm blobs are opaque
// to the hazard recognizer (guide rule #18 class), and R17 made the lacc MFMA
// the FIRST consumer of pa (distance ~0 from the asm permlane writes).
// Builtins let the compiler insert the required wait states. Asm fallback
// adds s_nop 3 + sched_barrier(0). Everything else identical to R17
// (= R16 base, proven 44.7us attn / 127.7 total).

#define B_   16
#define NQ_  2048
#define NK_  2048
#define D_   128
#define DV_  128
#define NTASK_ 512

typedef unsigned short ushort;
typedef __attribute__((ext_vector_type(4))) float          f32x4;
typedef __attribute__((ext_vector_type(8))) __bf16         bf16x8;
typedef __attribute__((ext_vector_type(8))) unsigned short ushort8v;
typedef __attribute__((ext_vector_type(4))) unsigned int   uint4v;
typedef __attribute__((ext_vector_type(2))) unsigned int   uint2v;

#ifdef __has_builtin
#if __has_builtin(__builtin_amdgcn_cvt_pk_bf16_f32)
#define HAVE_CVT_PK_BF16 1
#endif
#if __has_builtin(__builtin_amdgcn_permlane32_swap) && __has_builtin(__builtin_amdgcn_permlane16_swap)
#define HAVE_PERMLANE_SWAP 1
#endif
#endif

__device__ __forceinline__ ushort f2bf(float f) {
    unsigned u = __builtin_bit_cast(unsigned, f);
    return (ushort)((u + 0x8000u) >> 16);
}
__device__ __forceinline__ unsigned f2bf2(float a, float b) {
#ifdef HAVE_CVT_PK_BF16
    auto t = __builtin_amdgcn_cvt_pk_bf16_f32(a, b);
    return __builtin_bit_cast(unsigned, t);
#else
    return (unsigned)f2bf(a) | ((unsigned)f2bf(b) << 16);
#endif
}
// raw HW exp2: v_exp_f32 computes 2^x exactly; handles -1e30 -> 0, no wrapper.
__device__ __forceinline__ float exp2_hw(float x) {
    float r;
    asm("v_exp_f32 %0, %1" : "=v"(r) : "v"(x));
    return r;
}
__device__ __forceinline__ void gl_lds16(const ushort* g, ushort* l) {
    __builtin_amdgcn_global_load_lds(
        (const __attribute__((address_space(1))) void*)g,
        (__attribute__((address_space(3))) void*)l, 16, 0, 0);
}

// Pre-pass: per (b, k-tile): K -> bf16 tile [key64][d128], 16B-unit swizzle
// (d-unit du stored at du ^ (key&7)); V -> bf16 transposed [dv128][key64],
// key-unit kg stored at kg ^ (dv&7). V transposed via LDS.
#define VL_STRIDE 132
__global__ __launch_bounds__(256) void convert_kv(
    const float* __restrict__ K, const float* __restrict__ V,
    const int* __restrict__ vlen, ushort* __restrict__ Kb, ushort* __restrict__ Vtb)
{
    __shared__ ushort Vl[64 * VL_STRIDE];   // 16.5 KB
    const int id = blockIdx.x;              // 512 = 16 b x 32 tiles
    const int b  = id & 15, kt = id >> 4;
    if (kt >= ((vlen[b] + 63) >> 6)) return;
    const int tid = threadIdx.x;
    const float* gK = K + ((size_t)b * NK_ + kt * 64) * D_;
    const float* gV = V + ((size_t)b * NK_ + kt * 64) * DV_;
    ushort* tK = Kb  + ((size_t)b * 32 + kt) * 8192;
    ushort* tV = Vtb + ((size_t)b * 32 + kt) * 8192;

    #pragma unroll
    for (int i = 0; i < 4; ++i) {           // 1024 K units: key = u>>4, d-unit = u&15
        int u = i * 256 + tid;
        int key = u >> 4, d8 = u & 15;
        const float* p = gK + key * D_ + d8 * 8;
        f32x4 a0 = *(const f32x4*)p;
        f32x4 a1 = *(const f32x4*)(p + 4);
        uint4v w;
        w[0] = f2bf2(a0[0], a0[1]); w[1] = f2bf2(a0[2], a0[3]);
        w[2] = f2bf2(a1[0], a1[1]); w[3] = f2bf2(a1[2], a1[3]);
        *(uint4v*)&tK[key * 128 + ((d8 ^ (key & 7)) << 3)] = w;
    }

    // ---- V phase 1: coalesced row loads -> bf16 -> LDS [64][VL_STRIDE]
    #pragma unroll
    for (int i = 0; i < 4; ++i) {
        int u = i * 256 + tid;
        int key = u >> 4, d8 = u & 15;
        const float* p = gV + key * DV_ + d8 * 8;
        f32x4 a0 = *(const f32x4*)p;
        f32x4 a1 = *(const f32x4*)(p + 4);
        uint4v w;
        w[0] = f2bf2(a0[0], a0[1]); w[1] = f2bf2(a0[2], a0[3]);
        w[2] = f2bf2(a1[0], a1[1]); w[3] = f2bf2(a1[2], a1[3]);
        *(uint4v*)&Vl[key * VL_STRIDE + d8 * 8] = w;
    }
    __syncthreads();

    // ---- V phase 2: column gather from LDS, coalesced 16B writes to tV.
    #pragma unroll
    for (int i = 0; i < 4; ++i) {
        int u  = i * 256 + tid;             // 1024 units: c = u&7, dv = u>>3
        int c  = u & 7, dv = u >> 3;
        int kg = c ^ (dv & 7);
        ushort v[8];
        #pragma unroll
        for (int j = 0; j < 8; ++j) v[j] = Vl[(kg * 8 + j) * VL_STRIDE + dv];
        uint4v w;
        w[0] = (unsigned)v[0] | ((unsigned)v[1] << 16);
        w[1] = (unsigned)v[2] | ((unsigned)v[3] << 16);
        w[2] = (unsigned)v[4] | ((unsigned)v[5] << 16);
        w[3] = (unsigned)v[6] | ((unsigned)v[7] << 16);
        *(uint4v*)&tV[dv * 64 + c * 8] = w;
    }
}

__global__ __launch_bounds__(512, 4) void attn_fwd(
    const float* __restrict__ Q, const int* __restrict__ vlen,
    const ushort* __restrict__ Kb, const ushort* __restrict__ Vtb,
    float* __restrict__ Out)
{
    // double-buffered K|V tiles (bf16, swizzled): [buf][ K 8192 | V 8192 ]
    __shared__ ushort KVbuf[2][16384];                 // 64 KB
    __shared__ float  lsh[2][64];
    __shared__ int    ssch[16];
    float* Osh = (float*)&KVbuf[0][0];                 // epilogue alias: [wk][64q][128dv]

    const int tid  = threadIdx.x;     // 0..511
    const int w    = tid >> 6;        // 0..7
    const int wq   = w >> 1;          // q-sixteenth owner (16 rows)
    const int wk   = w & 1;           // key-half (32 keys)
    const int L    = tid & 63;
    const int col  = L & 15;
    const int quad = L >> 4;

    // ---- inline schedule: rank batches by vl desc
    if (tid < 16) {
        int my = vlen[tid];
        int rank = 0;
        for (int o = 0; o < 16; ++o) {
            int vo = vlen[o];
            if (vo > my || (vo == my && o < tid)) ++rank;
        }
        ssch[rank] = tid;
    }
    __syncthreads();

    // ---- R7 decode: pair rank p with 15-p; halves e and e+256.
    const int e     = blockIdx.x;
    const int p_    = (e & 255) >> 5;
    const int b     = (e >> 8) ? ssch[15 - p_] : ssch[p_];
    const int qbase = (e & 31) * 64;
    const int vl    = vlen[b];
    const int ntiles = (vl + 63) >> 6;

    const ushort* tKb = Kb  + (size_t)b * 32 * 8192;
    const ushort* tVb = Vtb + (size_t)b * 32 * 8192;

    #define ISSUE_DMA(KT, BUF)                                               \
        do {                                                                 \
            const ushort* gk = tKb + (size_t)(KT) * 8192;                    \
            const ushort* gv = tVb + (size_t)(KT) * 8192;                    \
            _Pragma("unroll")                                                \
            for (int i = 0; i < 2; ++i) {                                    \
                int off = (i * 512 + tid) * 8;                               \
                gl_lds16(gk + off, &KVbuf[BUF][off]);                        \
                gl_lds16(gv + off, &KVbuf[BUF][8192 + off]);                 \
            }                                                                \
        } while (0)

    // first-tile DMA issued BEFORE Q prep: HBM latency hides under Q load/convert
    ISSUE_DMA(0, 0);

    // ---- Q fragments (16 rows/wave), pre-scaled by log2(e)/sqrt(128)
    const float qscale = 0.12751743f;
    bf16x8 qf[4];
    {
        const int qrow = qbase + wq * 16 + col;
        const float* gQ = Q + ((size_t)b * NQ_ + qrow) * D_;
        #pragma unroll
        for (int c = 0; c < 4; ++c) {
            const float* pp = gQ + c * 32 + quad * 8;
            f32x4 a0 = *(const f32x4*)pp;
            f32x4 a1 = *(const f32x4*)(pp + 4);
            uint4v us;
            us[0] = f2bf2(a0[0] * qscale, a0[1] * qscale);
            us[1] = f2bf2(a0[2] * qscale, a0[3] * qscale);
            us[2] = f2bf2(a1[0] * qscale, a1[1] * qscale);
            us[3] = f2bf2(a1[2] * qscale, a1[3] * qscale);
            qf[c] = __builtin_bit_cast(bf16x8, us);
        }
    }

    // ---- ones B-fragment for row-sum MFMA (bf16 1.0 x8)
    uint4v onesu;
    onesu[0] = 0x3F803F80u; onesu[1] = 0x3F803F80u;
    onesu[2] = 0x3F803F80u; onesu[3] = 0x3F803F80u;
    const bf16x8 onesb = __builtin_bit_cast(bf16x8, onesu);

    // ---- accumulators: partial O over own key-half, full 128 dv; lacc = row-sums
    f32x4 o[8];
    #pragma unroll
    for (int d = 0; d < 8; ++d) o[d] = (f32x4){0.f, 0.f, 0.f, 0.f};
    f32x4 lacc = (f32x4){0.f, 0.f, 0.f, 0.f};

    const int swz = col & 7;

    for (int kt = 0; kt < ntiles; ++kt) {
        const int buf = kt & 1;
        __syncthreads();   // drains DMA(kt); prev readers done
        if (kt + 1 < ntiles) ISSUE_DMA(kt + 1, buf ^ 1);

        const ushort* Kt = &KVbuf[buf][0];
        const ushort* Vt = &KVbuf[buf][8192];

        // ---- ALL 8 K-fragment reads first (in flight before MFMAs need them)
        const int key0 = (wk * 32 + col) * 128;
        bf16x8 kb0[4], kb1[4];
        #pragma unroll
        for (int c = 0; c < 4; ++c) {
            kb0[c] = __builtin_bit_cast(bf16x8, *(const ushort8v*)
                &Kt[key0 + (((c * 4 + quad) ^ swz) << 3)]);
            kb1[c] = __builtin_bit_cast(bf16x8, *(const ushort8v*)
                &Kt[key0 + 16 * 128 + (((c * 4 + quad) ^ swz) << 3)]);
        }

        // ---- S^T = K Q^T (swapped): lane holds S[q=col][key=kc*16+quad*4+r]
        f32x4 s0 = (f32x4){0.f,0.f,0.f,0.f};
        f32x4 s1 = (f32x4){0.f,0.f,0.f,0.f};
        #pragma unroll
        for (int c = 0; c < 4; ++c) {
            s0 = __builtin_amdgcn_mfma_f32_16x16x32_bf16(kb0[c], qf[c], s0, 0, 0, 0);
            s1 = __builtin_amdgcn_mfma_f32_16x16x32_bf16(kb1[c], qf[c], s1, 0, 0, 0);
        }

        // ---- prefetch V fragments NOW (no dep on softmax): LDS latency
        // hides under the exp2/permlane serial chain below.
        bf16x8 vbr[8];
        #pragma unroll
        for (int dvc = 0; dvc < 8; ++dvc) {
            const int dv = dvc * 16 + col;
            vbr[dvc] = __builtin_bit_cast(bf16x8, *(const ushort8v*)
                &Vt[dv * 64 + (((wk * 4 + quad) ^ swz) << 3)]);
        }

        // ---- mask (key rows lane-indexed); exp2(-1e30) == 0
        const int rem = vl - kt * 64 - wk * 32;   // valid keys in this half
        if (rem < 32) {
            #pragma unroll
            for (int rr = 0; rr < 4; ++rr) {
                if (quad * 4 + rr >= rem)      s0[rr] = -1e30f;
                if (16 + quad * 4 + rr >= rem) s1[rr] = -1e30f;
            }
        }

        // ---- p = exp2(s) -> packed bf16
        unsigned wA = f2bf2(exp2_hw(s0[0]), exp2_hw(s0[1]));
        unsigned wB = f2bf2(exp2_hw(s0[2]), exp2_hw(s0[3]));
        unsigned wC = f2bf2(exp2_hw(s1[0]), exp2_hw(s1[1]));
        unsigned wD = f2bf2(exp2_hw(s1[2]), exp2_hw(s1[3]));

        // ---- in-register C-layout -> A-layout transpose across quads.
        // Builtins (not asm) so the hazard recognizer models the VALU writes
        // that the following MFMAs read (R17's suspected failure mode).
#ifdef HAVE_PERMLANE_SWAP
        {
            uint2v t;
            t = __builtin_amdgcn_permlane32_swap(wA, wC, false, false); wA = t[0]; wC = t[1];
            t = __builtin_amdgcn_permlane32_swap(wB, wD, false, false); wB = t[0]; wD = t[1];
            t = __builtin_amdgcn_permlane16_swap(wA, wC, false, false); wA = t[0]; wC = t[1];
            t = __builtin_amdgcn_permlane16_swap(wB, wD, false, false); wB = t[0]; wD = t[1];
        }
#else
        asm("v_permlane32_swap_b32 %0, %1" : "+v"(wA), "+v"(wC));
        asm("v_permlane32_swap_b32 %0, %1" : "+v"(wB), "+v"(wD));
        asm("v_permlane16_swap_b32 %0, %1" : "+v"(wA), "+v"(wC));
        asm("v_permlane16_swap_b32 %0, %1" : "+v"(wB), "+v"(wD));
        __builtin_amdgcn_sched_barrier(0);
        asm volatile("s_nop 3");           // VALU(asm)->MFMA read hazard cover
        __builtin_amdgcn_sched_barrier(0);
#endif
        uint4v pw;
        pw[0] = wA; pw[1] = wB; pw[2] = wC; pw[3] = wD;
        bf16x8 pa = __builtin_bit_cast(bf16x8, pw);

        // ---- row-sums via matrix pipe: lacc = mfma(pa, ones) == PV pattern
        // with B=ones -> lacc[rr] = rowsum(q = quad*4+rr), same for all col.
        lacc = __builtin_amdgcn_mfma_f32_16x16x32_bf16(pa, onesb, lacc, 0, 0, 0);

        // ---- O_partial += P_own(16q x 32k) V_own(32k x 128dv)
        #pragma unroll
        for (int dvc = 0; dvc < 8; ++dvc)
            o[dvc] = __builtin_amdgcn_mfma_f32_16x16x32_bf16(pa, vbr[dvc], o[dvc], 0, 0, 0);
    }
    #undef ISSUE_DMA

    __syncthreads();   // everyone done with KVbuf before aliasing as Osh

    // lacc reg rr holds rowsum for wave-local q row quad*4+rr (same for all col)
    if (col == 0) {
        #pragma unroll
        for (int rr = 0; rr < 4; ++rr)
            lsh[wk][wq * 16 + quad * 4 + rr] = lacc[rr];
    }
    #pragma unroll
    for (int dvc = 0; dvc < 8; ++dvc)
        #pragma unroll
        for (int rr = 0; rr < 4; ++rr)
            Osh[wk * 8192 + (wq * 16 + quad * 4 + rr) * 128 + dvc * 16 + col]
                = o[dvc][rr];
    __syncthreads();

    // ---- combine wk halves, normalize, coalesced store
    float* gO = Out + ((size_t)b * NQ_ + qbase) * DV_;
    #pragma unroll
    for (int i = 0; i < 4; ++i) {
        int idx = i * 512 + tid;           // f32x4 chunk id, row-major
        int row = idx >> 5;
        int dq  = idx & 31;
        f32x4 a0 = *(const f32x4*)&Osh[row * 128 + dq * 4];
        f32x4 a1 = *(const f32x4*)&Osh[8192 + row * 128 + dq * 4];
        float linv = 1.0f / (lsh[0][row] + lsh[1][row]);
        *(f32x4*)&gO[(size_t)row * DV_ + dq * 4] = (a0 + a1) * linv;
    }
}

extern "C" void kernel_launch(void* const* d_in, const int* in_sizes, int n_in,
                              void* d_out, int out_size, void* d_ws, size_t ws_size,
                              hipStream_t stream) {
    const float* Q  = (const float*)d_in[0];
    const float* K  = (const float*)d_in[1];
    const float* V  = (const float*)d_in[2];
    const int*   vl = (const int*)d_in[3];
    float* out = (float*)d_out;

    // ws: [0,4K) reserved | [4K, +8.39M) Kb | [next, +8.39M) Vtb  (~16.8 MB)
    char* ws = (char*)d_ws;
    ushort* Kbuf = (ushort*)(ws + 4096);
    ushort* Vbuf = Kbuf + (size_t)B_ * 32 * 8192;

    convert_kv<<<dim3(512, 1, 1), dim3(256, 1, 1), 0, stream>>>(K, V, vl, Kbuf, Vbuf);
    attn_fwd<<<dim3(NTASK_, 1, 1), dim3(512, 1, 1), 0, stream>>>(
        Q, vl, Kbuf, Vbuf, out);
}